// Round 2
// baseline (489.472 us; speedup 1.0000x reference)
//
#include <hip/hip_runtime.h>

typedef float f32x4 __attribute__((ext_vector_type(4)));
typedef float f32x16 __attribute__((ext_vector_type(16)));
typedef __bf16 bf16x8 __attribute__((ext_vector_type(8)));
typedef unsigned int u32x4 __attribute__((ext_vector_type(4)));
typedef unsigned short ushort_t;

// ---------------------------------------------------------------- fp32 -> bf16 (RNE)
__device__ __forceinline__ unsigned short f2bf(float f) {
    unsigned u = __float_as_uint(f);
    u += 0x7FFFu + ((u >> 16) & 1u);   // round-nearest-even (inputs finite)
    return (unsigned short)(u >> 16);
}

// One fused cast kernel for both x and W (unchanged, verified).
__global__ __launch_bounds__(256) void cast_both(const f32x4* __restrict__ x, u32x4* __restrict__ xo,
                                                 const f32x4* __restrict__ w, u32x4* __restrict__ wo) {
    long t = (long)blockIdx.x * 256 + threadIdx.x;
    const f32x4* src;
    u32x4* dst;
    long j;
    if (t < 4194304L) { src = x; dst = xo; j = t; }
    else              { src = w; dst = wo; j = t - 4194304L; }
    f32x4 a = __builtin_nontemporal_load(&src[2 * j]);
    f32x4 b = __builtin_nontemporal_load(&src[2 * j + 1]);
    u32x4 v;
    v.x = (unsigned)f2bf(a.x) | ((unsigned)f2bf(a.y) << 16);
    v.y = (unsigned)f2bf(a.z) | ((unsigned)f2bf(a.w) << 16);
    v.z = (unsigned)f2bf(b.x) | ((unsigned)f2bf(b.y) << 16);
    v.w = (unsigned)f2bf(b.z) | ((unsigned)f2bf(b.w) << 16);
    dst[j] = v;
}

// ---------------------------------------------------------------- 256x256 pipelined bf16 MFMA GEMM
// out[m,n] = sum_k A[m,k]*B[n,k] + bias[n].  A:[8192,4096] bf16, B:[4096,4096] bf16, row-major.
// BM=BN=256, BK=64, 8 waves in 4M x 2N grid -> per-wave 64x128 via 2x4 of 32x32x16 MFMA.
// Each wave reads exactly ONE A-half (its 64 rows) and ONE B-half -> per-phase frag reads = 6.
// 4 phases/tile = 4 K16-steps; fragment reads for phase p issued during phase p-1 (double-
// buffered reg sets X/Y), draining under the previous MFMA cluster (compiler fine lgkmcnt).
// Staging: all 8 global_load_lds for tile t+2 issued at tile t p3, AFTER lgkm-drain+barrier
// (deterministic WAR safety on buf b); vmcnt(0) at p3 drains only tile-(t-1)'s stages (1 tile
// in flight -> no stall).  16B-block XOR swizzle slot = kb ^ (row&7) (verified 0-conflict).
constexpr int KD = 4096;

#define GLOAD_LDS(gp, lp) __builtin_amdgcn_global_load_lds( \
    (const __attribute__((address_space(1))) unsigned int*)(gp), \
    (__attribute__((address_space(3))) unsigned int*)(lp), 16, 0, 0)

#define BARRIER()    __builtin_amdgcn_s_barrier()
#define WAIT_LGKM0() asm volatile("s_waitcnt lgkmcnt(0)" ::: "memory")
#define WAIT_VM(n)   asm volatile("s_waitcnt vmcnt(" #n ")" ::: "memory")

__global__ __launch_bounds__(512, 2) void gemm256(const ushort_t* __restrict__ A,
                                                  const ushort_t* __restrict__ B,
                                                  const float* __restrict__ bias,
                                                  float* __restrict__ out) {
    __shared__ char lds[131072];
    // A: (buf*2+half)*16384 ; B: 65536 + (buf*2+half)*16384.  half = 128 rows x 64 K x 2B.

    const int tid  = threadIdx.x;
    const int lane = tid & 63;
    const int wave = tid >> 6;      // 0..7
    const int wr   = wave >> 1;     // 0..3 (M)
    const int wc   = wave & 1;      // 0..1 (N)
    const int l31  = lane & 31;
    const int hi   = lane >> 5;     // k-block within K16 step

    // XCD-aware bijective swizzle (512 blocks % 8 == 0)
    const int bid = blockIdx.x;
    const int swz = (bid & 7) * 64 + (bid >> 3);
    const int m0  = (swz >> 4) * 256;
    const int n0  = (swz & 15) * 256;

    // staging geometry: slot c = tid&7 at row srow holds source 16B-block c ^ (srow&7)
    const int srow = tid >> 3;
    const int koff = ((tid & 7) ^ (srow & 7)) * 8;
    const int ldst = tid * 16;
    const ushort_t* gA = A + (size_t)m0 * KD + koff;
    const ushort_t* gB = B + (size_t)n0 * KD + koff;

    // fragment LDS addresses.  row&7 == lane&7 for all fragment rows.
    // swizzled 16B slot for step s, k-block hi: (2s+hi) ^ (row&7) = (hi^(lane&7)) ^ (s<<1)
    //   -> byte addr = P ^ (s<<5) with P = regionbase + row*128 + ((hi^(lane&7))<<4)
    const int bx  = (hi ^ (lane & 7)) << 4;
    const int hA  = wr >> 1;              // which A half this wave reads
    const int rba = (wr & 1) * 64;        // row base within that half
    const int PA0 = hA * 16384 + (rba +  0 + l31) * 128 + bx;
    const int PA1 = hA * 16384 + (rba + 32 + l31) * 128 + bx;
    const int PB0 = 65536 + wc * 16384 + ( 0 + l31) * 128 + bx;
    const int PB1 = 65536 + wc * 16384 + (32 + l31) * 128 + bx;
    const int PB2 = 65536 + wc * 16384 + (64 + l31) * 128 + bx;
    const int PB3 = 65536 + wc * 16384 + (96 + l31) * 128 + bx;

#define LOAD_AV(dst, bB, sK) do { \
    dst[0] = *(const bf16x8*)(lds + (bB) + (PA0 ^ (sK))); \
    dst[1] = *(const bf16x8*)(lds + (bB) + (PA1 ^ (sK))); \
} while (0)

#define LOAD_BV(dst, bB, sK) do { \
    dst[0] = *(const bf16x8*)(lds + (bB) + (PB0 ^ (sK))); \
    dst[1] = *(const bf16x8*)(lds + (bB) + (PB1 ^ (sK))); \
    dst[2] = *(const bf16x8*)(lds + (bB) + (PB2 ^ (sK))); \
    dst[3] = *(const bf16x8*)(lds + (bB) + (PB3 ^ (sK))); \
} while (0)

#define STAGE_ALL(bB, kt) do { \
    GLOAD_LDS(gA + (size_t)(  0 + srow) * KD + (kt), lds + (bB) +             0 + ldst); \
    GLOAD_LDS(gA + (size_t)( 64 + srow) * KD + (kt), lds + (bB) +          8192 + ldst); \
    GLOAD_LDS(gA + (size_t)(128 + srow) * KD + (kt), lds + (bB) +         16384 + ldst); \
    GLOAD_LDS(gA + (size_t)(192 + srow) * KD + (kt), lds + (bB) +         24576 + ldst); \
    GLOAD_LDS(gB + (size_t)(  0 + srow) * KD + (kt), lds + (bB) + 65536 +     0 + ldst); \
    GLOAD_LDS(gB + (size_t)( 64 + srow) * KD + (kt), lds + (bB) + 65536 +  8192 + ldst); \
    GLOAD_LDS(gB + (size_t)(128 + srow) * KD + (kt), lds + (bB) + 65536 + 16384 + ldst); \
    GLOAD_LDS(gB + (size_t)(192 + srow) * KD + (kt), lds + (bB) + 65536 + 24576 + ldst); \
} while (0)

    f32x16 acc[2][4];
#pragma unroll
    for (int mi = 0; mi < 2; ++mi)
#pragma unroll
        for (int nj = 0; nj < 4; ++nj)
#pragma unroll
            for (int r = 0; r < 16; ++r) acc[mi][nj][r] = 0.f;

    bf16x8 avX[2], bvX[4], avY[2], bvY[4];

#define MFMA_PHASE(av, bv) do { \
    __builtin_amdgcn_s_setprio(1); \
    _Pragma("unroll") for (int mi = 0; mi < 2; ++mi) \
    _Pragma("unroll") for (int nj = 0; nj < 4; ++nj) \
        acc[mi][nj] = __builtin_amdgcn_mfma_f32_32x32x16_bf16(av[mi], bv[nj], acc[mi][nj], 0, 0, 0); \
    __builtin_amdgcn_s_setprio(0); \
} while (0)

// One K-tile on buffer base bB (0 or 32768), other buffer obB.
// DO_STG / DO_PREF are compile-time 0/1.
#define TILE(bB, obB, DO_STG, kt2, DO_PREF) do { \
    /* p0: compute X(s0); read s1 -> Y */ \
    LOAD_AV(avY, bB, 32); LOAD_BV(bvY, bB, 32); \
    BARRIER(); MFMA_PHASE(avX, bvX); BARRIER(); \
    /* p1: compute Y(s1); read s2 -> X */ \
    LOAD_AV(avX, bB, 64); LOAD_BV(bvX, bB, 64); \
    BARRIER(); MFMA_PHASE(avY, bvY); BARRIER(); \
    /* p2: compute X(s2); read s3 -> Y */ \
    LOAD_AV(avY, bB, 96); LOAD_BV(bvY, bB, 96); \
    BARRIER(); MFMA_PHASE(avX, bvX); BARRIER(); \
    /* p3: all waves' reads of bB done (lgkm0+barrier) -> restage bB; prev-tile stages */ \
    /* landed (vm0+barrier) -> prefetch next tile's s0 from obB; compute Y(s3) */ \
    WAIT_LGKM0(); WAIT_VM(0); BARRIER(); \
    if (DO_STG) { STAGE_ALL(bB, kt2); } \
    if (DO_PREF) { LOAD_AV(avX, obB, 0); LOAD_BV(bvX, obB, 0); } \
    MFMA_PHASE(avY, bvY); BARRIER(); \
} while (0)

    // prologue: stage tile0 -> buf0, tile1 -> buf1; wait tile0 (8 newest still in flight);
    // barrier makes ALL waves' tile0 data visible; prefetch tile0 s0.
    STAGE_ALL(0, 0);
    STAGE_ALL(32768, 64);
    WAIT_VM(8);
    BARRIER();
    LOAD_AV(avX, 0, 0); LOAD_BV(bvX, 0, 0);

    // tiles 0..61 stage t+2; 62 prefetches 63; 63 pure compute.
    for (int tp = 0; tp < 31; ++tp) {
        const int kt = tp * 128;
        TILE(0,     32768, 1, kt + 128, 1);
        TILE(32768, 0,     1, kt + 192, 1);
    }
    TILE(0,     32768, 0, 0, 1);   // t = 62
    TILE(32768, 0,     0, 0, 0);   // t = 63

    // epilogue: 32x32 C/D layout: col = lane&31, row = (reg&3) + 8*(reg>>2) + 4*(lane>>5)
    const int cb = n0 + wc * 128 + l31;
    float bb[4];
#pragma unroll
    for (int nj = 0; nj < 4; ++nj) bb[nj] = bias[cb + nj * 32];

    const int rbase = m0 + wr * 64 + hi * 4;
#pragma unroll
    for (int mi = 0; mi < 2; ++mi)
#pragma unroll
        for (int nj = 0; nj < 4; ++nj)
#pragma unroll
            for (int r = 0; r < 16; ++r) {
                const int row = rbase + mi * 32 + (r & 3) + (r >> 2) * 8;
                out[(size_t)row * 4096 + cb + nj * 32] = acc[mi][nj][r] + bb[nj];
            }
}

// ---------------------------------------------------------------- fp32 fallback (only if ws too small)
__global__ __launch_bounds__(256) void gemm_f32_fallback(const float* __restrict__ x,
                                                         const float* __restrict__ W,
                                                         const float* __restrict__ bias,
                                                         float* __restrict__ out) {
    __shared__ float As[32][33];
    __shared__ float Bs[32][33];
    const int tx = threadIdx.x & 31, ty = threadIdx.x >> 5;   // ty 0..7
    const int m0 = blockIdx.y * 32, n0 = blockIdx.x * 32;
    float acc[4] = {0.f, 0.f, 0.f, 0.f};
    for (int k0 = 0; k0 < 4096; k0 += 32) {
#pragma unroll
        for (int i = 0; i < 4; ++i) {
            As[ty + 8 * i][tx] = x[(size_t)(m0 + ty + 8 * i) * 4096 + k0 + tx];
            Bs[ty + 8 * i][tx] = W[(size_t)(n0 + ty + 8 * i) * 4096 + k0 + tx];
        }
        __syncthreads();
#pragma unroll 8
        for (int kk = 0; kk < 32; ++kk) {
            const float bv = Bs[tx][kk];
#pragma unroll
            for (int i = 0; i < 4; ++i) acc[i] += As[ty + 8 * i][kk] * bv;
        }
        __syncthreads();
    }
#pragma unroll
    for (int i = 0; i < 4; ++i)
        out[(size_t)(m0 + ty + 8 * i) * 4096 + n0 + tx] = acc[i] + bias[n0 + tx];
}

// ---------------------------------------------------------------- launch
extern "C" void kernel_launch(void* const* d_in, const int* in_sizes, int n_in,
                              void* d_out, int out_size, void* d_ws, size_t ws_size,
                              hipStream_t stream) {
    const float* x = (const float*)d_in[0];   // [8192, 4096]
    const float* W = (const float*)d_in[1];   // [4096, 4096]
    const float* b = (const float*)d_in[2];   // [4096]
    float* out = (float*)d_out;               // [8192, 4096]

    constexpr size_t T = 8192, DIN = 4096, DOUT = 4096;
    const size_t nx = T * DIN, nw = DOUT * DIN;

    if (ws_size >= (nx + nw) * sizeof(unsigned short)) {
        unsigned short* xbf = (unsigned short*)d_ws;
        unsigned short* wbf = xbf + nx;
        cast_both<<<24576, 256, 0, stream>>>((const f32x4*)x, (u32x4*)xbf,
                                             (const f32x4*)W, (u32x4*)wbf);
        // 256x256 tiles: 32 x 16 = 512 blocks, 512 threads
        gemm256<<<512, 512, 0, stream>>>(xbf, wbf, b, out);
    } else {
        dim3 grid(DOUT / 32, T / 32);
        gemm_f32_fallback<<<grid, 32 * 8, 0, stream>>>(x, W, b, out);
    }
}

// Round 3
// 457.508 us; speedup vs baseline: 1.0699x; 1.0699x over previous
//
#include <hip/hip_runtime.h>

typedef float f32x4 __attribute__((ext_vector_type(4)));
typedef __bf16 bf16x8 __attribute__((ext_vector_type(8)));
typedef unsigned int u32x4 __attribute__((ext_vector_type(4)));
typedef unsigned short ushort_t;

// ---------------------------------------------------------------- fp32 -> bf16 (RNE)
__device__ __forceinline__ unsigned short f2bf(float f) {
    unsigned u = __float_as_uint(f);
    u += 0x7FFFu + ((u >> 16) & 1u);   // round-nearest-even (inputs finite)
    return (unsigned short)(u >> 16);
}

// One fused cast kernel for both x and W (unchanged, verified).
__global__ __launch_bounds__(256) void cast_both(const f32x4* __restrict__ x, u32x4* __restrict__ xo,
                                                 const f32x4* __restrict__ w, u32x4* __restrict__ wo) {
    long t = (long)blockIdx.x * 256 + threadIdx.x;
    const f32x4* src;
    u32x4* dst;
    long j;
    if (t < 4194304L) { src = x; dst = xo; j = t; }
    else              { src = w; dst = wo; j = t - 4194304L; }
    f32x4 a = __builtin_nontemporal_load(&src[2 * j]);
    f32x4 b = __builtin_nontemporal_load(&src[2 * j + 1]);
    u32x4 v;
    v.x = (unsigned)f2bf(a.x) | ((unsigned)f2bf(a.y) << 16);
    v.y = (unsigned)f2bf(a.z) | ((unsigned)f2bf(a.w) << 16);
    v.z = (unsigned)f2bf(b.x) | ((unsigned)f2bf(b.y) << 16);
    v.w = (unsigned)f2bf(b.z) | ((unsigned)f2bf(b.w) << 16);
    dst[j] = v;
}

// ---------------------------------------------------------------- 256x256 8-phase bf16 MFMA GEMM
// R1 skeleton (verified: passed, 0 bank conflicts, 241us) + cross-phase fragment prefetch:
//   - reads for quadrant p issued during phase p-1 into double-buffered reg sets
//   - av0 = A-half0 set, av1 = A-half1 set (stable roles)
//   - bv sets swap roles per tile: BVLO holds B-half0 (prefetched prev p3), BVHI gets B-half1
//     at p0-issue and next tile's B-half0 at p3-prefetch
//   - no explicit lgkmcnt(0): compiler's register-dep s_waitcnt counts per-operand
//   - WAR safety: each region's reads are consumed by an MFMA (reg-dep lgkm wait) >= one
//     barrier before that region is restaged (A0@p1, B1@p2, A1@p3, B0@next-p0)
//   - p3 prefetch (next-tile A0/B0) sits after vmcnt(6)+barrier: vmcnt(6) retires exactly
//     through this tile's STG0 = B0(t+1); A0(t+1) was staged a full tile earlier.
constexpr int KD = 4096;

#define GLOAD_LDS(gp, lp) __builtin_amdgcn_global_load_lds( \
    (const __attribute__((address_space(1))) unsigned int*)(gp), \
    (__attribute__((address_space(3))) unsigned int*)(lp), 16, 0, 0)

#define BARRIER() do { asm volatile("" ::: "memory"); __builtin_amdgcn_s_barrier(); \
                       asm volatile("" ::: "memory"); } while (0)
#define WAIT_VM(n)   asm volatile("s_waitcnt vmcnt(" #n ")" ::: "memory")

__global__ __launch_bounds__(512, 2) void gemm256(const ushort_t* __restrict__ A,
                                                  const ushort_t* __restrict__ B,
                                                  const float* __restrict__ bias,
                                                  float* __restrict__ out) {
    __shared__ char lds[131072];
    // A half-tiles at (buf*2+half)*16384, B half-tiles at 65536 + (buf*2+half)*16384

    const int tid  = threadIdx.x;
    const int lane = tid & 63;
    const int wave = tid >> 6;      // 0..7
    const int wr   = wave >> 2;     // 0..1  (M)
    const int wc   = wave & 3;      // 0..3  (N)
    const int q    = lane >> 4;
    const int ml   = lane & 15;

    // XCD-aware bijective swizzle (512 blocks % 8 == 0)
    const int bid = blockIdx.x;
    const int swz = (bid & 7) * 64 + (bid >> 3);
    const int m0  = (swz >> 4) * 256;
    const int n0  = (swz & 15) * 256;

    // staging: slot c = tid&7 of row srow holds source 16B-block c ^ (srow&7)
    const int srow = tid >> 3;
    const int koff = ((tid & 7) ^ (srow & 7)) * 8;
    const int ldst = tid * 16;
    const ushort_t* gA = A + (size_t)m0 * KD + koff;
    const ushort_t* gB = B + (size_t)n0 * KD + koff;

#define STAGE_A(buf, half, kt) do { \
    const ushort_t* _g = gA + (size_t)((half) * 128 + srow) * KD + (kt); \
    char* _l = lds + ((buf) * 2 + (half)) * 16384 + ldst; \
    GLOAD_LDS(_g, _l); \
    GLOAD_LDS(_g + (size_t)64 * KD, _l + 8192); \
} while (0)

#define STAGE_B(buf, half, kt) do { \
    const ushort_t* _g = gB + (size_t)((half) * 128 + srow) * KD + (kt); \
    char* _l = lds + 65536 + ((buf) * 2 + (half)) * 16384 + ldst; \
    GLOAD_LDS(_g, _l); \
    GLOAD_LDS(_g + (size_t)64 * KD, _l + 8192); \
} while (0)

    // fragment read byte-offsets within a 16KB half-tile (row&7 == ml&7 for all rows)
    int offA[4][2], offB[2][2];
#pragma unroll
    for (int mi = 0; mi < 4; ++mi)
#pragma unroll
        for (int s = 0; s < 2; ++s)
            offA[mi][s] = (wr * 64 + mi * 16 + ml) * 128 + (((s * 4 + q) ^ (ml & 7)) << 4);
#pragma unroll
    for (int nj = 0; nj < 2; ++nj)
#pragma unroll
        for (int s = 0; s < 2; ++s)
            offB[nj][s] = (wc * 32 + nj * 16 + ml) * 128 + (((s * 4 + q) ^ (ml & 7)) << 4);

    f32x4 acc[2][2][4][2];
#pragma unroll
    for (int a = 0; a < 2; ++a)
#pragma unroll
        for (int c = 0; c < 2; ++c)
#pragma unroll
            for (int d = 0; d < 4; ++d)
#pragma unroll
                for (int e = 0; e < 2; ++e) {
                    acc[a][c][d][e].x = 0.f; acc[a][c][d][e].y = 0.f;
                    acc[a][c][d][e].z = 0.f; acc[a][c][d][e].w = 0.f;
                }

    bf16x8 av0[4][2], av1[4][2], bv0[2][2], bv1[2][2];

#define LOAD_AV(dst, bI, mh) do { \
    const char* _b = lds + ((bI) * 2 + (mh)) * 16384; \
    _Pragma("unroll") for (int mi = 0; mi < 4; ++mi) \
    _Pragma("unroll") for (int s = 0; s < 2; ++s) \
        dst[mi][s] = *(const bf16x8*)(_b + offA[mi][s]); \
} while (0)

#define LOAD_BV(dst, bI, nh) do { \
    const char* _b = lds + 65536 + ((bI) * 2 + (nh)) * 16384; \
    _Pragma("unroll") for (int nj = 0; nj < 2; ++nj) \
    _Pragma("unroll") for (int s = 0; s < 2; ++s) \
        dst[nj][s] = *(const bf16x8*)(_b + offB[nj][s]); \
} while (0)

#define MFMA_Q(av, bv, mh, nh) do { \
    __builtin_amdgcn_s_setprio(1); \
    _Pragma("unroll") for (int s = 0; s < 2; ++s) \
    _Pragma("unroll") for (int mi = 0; mi < 4; ++mi) \
    _Pragma("unroll") for (int nj = 0; nj < 2; ++nj) \
        acc[mh][nh][mi][nj] = __builtin_amdgcn_mfma_f32_16x16x32_bf16(av[mi][s], bv[nj][s], acc[mh][nh][mi][nj], 0, 0, 0); \
    __builtin_amdgcn_s_setprio(0); \
} while (0)

// One K-tile on buffer index bI (0/1), next-tile buffer oI.
// BVLO holds this tile's B-half0 (prefetched at prev p3); BVHI is free on entry.
// Entering: av0 holds this tile's A-half0.
#define TILE(bI, oI, BVLO, BVHI, STG0, STG1, STG2, STG3, VMW, DO_PREF) do { \
    /* p0: Q(0,0) = av0 . BVLO ; issue B-half1 -> BVHI */ \
    LOAD_BV(BVHI, bI, 1); STG0; \
    BARRIER(); MFMA_Q(av0, BVLO, 0, 0); BARRIER(); \
    /* p1: Q(0,1) = av0 . BVHI ; issue A-half1 -> av1 */ \
    LOAD_AV(av1, bI, 1); STG1; \
    BARRIER(); MFMA_Q(av0, BVHI, 0, 1); BARRIER(); \
    /* p2: Q(1,1) = av1 . BVHI */ \
    STG2; \
    BARRIER(); MFMA_Q(av1, BVHI, 1, 1); BARRIER(); \
    /* p3: Q(1,0) = av1 . BVLO ; prefetch next tile's A-half0 -> av0, B-half0 -> BVHI */ \
    STG3; VMW; \
    BARRIER(); \
    if (DO_PREF) { LOAD_AV(av0, oI, 0); LOAD_BV(BVHI, oI, 0); } \
    MFMA_Q(av1, BVLO, 1, 0); BARRIER(); \
} while (0)

    // prologue: stage tile0 fully + tile1's A0,B1,A1 (B0(1) comes at t0-p0).
    // vmcnt(6): 14 outstanding -> retires the oldest 8 = ALL of tile0 (fixes R1's vmcnt(8) gap).
    STAGE_A(0, 0, 0);  STAGE_B(0, 0, 0);  STAGE_B(0, 1, 0);  STAGE_A(0, 1, 0);
    STAGE_A(1, 0, 64); STAGE_B(1, 1, 64); STAGE_A(1, 1, 64);
    WAIT_VM(6);
    BARRIER();
    LOAD_AV(av0, 0, 0); LOAD_BV(bv0, 0, 0);

    // tiles 0..61: steady staging (STG0 -> t+1's B0, STG1-3 -> t+2's A0,B1,A1), vmcnt(6)@p3.
#pragma unroll 1
    for (int tp = 0; tp < 31; ++tp) {
        const int kt = tp * 128;
        TILE(0, 1, bv0, bv1, STAGE_B(1, 0, kt + 64),  STAGE_A(0, 0, kt + 128),
                             STAGE_B(0, 1, kt + 128), STAGE_A(0, 1, kt + 128), WAIT_VM(6), 1);
        TILE(1, 0, bv1, bv0, STAGE_B(0, 0, kt + 128), STAGE_A(1, 0, kt + 192),
                             STAGE_B(1, 1, kt + 192), STAGE_A(1, 1, kt + 192), WAIT_VM(6), 1);
    }
    // t=62: stage only B0(63); drain everything; prefetch t63.  t=63: pure compute.
    TILE(0, 1, bv0, bv1, STAGE_B(1, 0, 4032), (void)0, (void)0, (void)0, WAIT_VM(0), 1);
    TILE(1, 0, bv1, bv0, (void)0, (void)0, (void)0, (void)0, (void)0, 0);

    // epilogue: C/D layout col=lane&15, row=q*4+reg (verified)
    float bb[2][2];
#pragma unroll
    for (int nh = 0; nh < 2; ++nh)
#pragma unroll
        for (int nj = 0; nj < 2; ++nj)
            bb[nh][nj] = bias[n0 + nh * 128 + wc * 32 + nj * 16 + ml];

#pragma unroll
    for (int mh = 0; mh < 2; ++mh)
#pragma unroll
        for (int nh = 0; nh < 2; ++nh)
#pragma unroll
            for (int mi = 0; mi < 4; ++mi)
#pragma unroll
                for (int nj = 0; nj < 2; ++nj) {
                    const int gc  = n0 + nh * 128 + wc * 32 + nj * 16 + ml;
                    const int gr0 = m0 + mh * 128 + wr * 64 + mi * 16 + q * 4;
#pragma unroll
                    for (int r = 0; r < 4; ++r)
                        out[(size_t)(gr0 + r) * 4096 + gc] = acc[mh][nh][mi][nj][r] + bb[nh][nj];
                }
}

// ---------------------------------------------------------------- fp32 fallback (only if ws too small)
__global__ __launch_bounds__(256) void gemm_f32_fallback(const float* __restrict__ x,
                                                         const float* __restrict__ W,
                                                         const float* __restrict__ bias,
                                                         float* __restrict__ out) {
    __shared__ float As[32][33];
    __shared__ float Bs[32][33];
    const int tx = threadIdx.x & 31, ty = threadIdx.x >> 5;   // ty 0..7
    const int m0 = blockIdx.y * 32, n0 = blockIdx.x * 32;
    float acc[4] = {0.f, 0.f, 0.f, 0.f};
    for (int k0 = 0; k0 < 4096; k0 += 32) {
#pragma unroll
        for (int i = 0; i < 4; ++i) {
            As[ty + 8 * i][tx] = x[(size_t)(m0 + ty + 8 * i) * 4096 + k0 + tx];
            Bs[ty + 8 * i][tx] = W[(size_t)(n0 + ty + 8 * i) * 4096 + k0 + tx];
        }
        __syncthreads();
#pragma unroll 8
        for (int kk = 0; kk < 32; ++kk) {
            const float bv = Bs[tx][kk];
#pragma unroll
            for (int i = 0; i < 4; ++i) acc[i] += As[ty + 8 * i][kk] * bv;
        }
        __syncthreads();
    }
#pragma unroll
    for (int i = 0; i < 4; ++i)
        out[(size_t)(m0 + ty + 8 * i) * 4096 + n0 + tx] = acc[i] + bias[n0 + tx];
}

// ---------------------------------------------------------------- launch
extern "C" void kernel_launch(void* const* d_in, const int* in_sizes, int n_in,
                              void* d_out, int out_size, void* d_ws, size_t ws_size,
                              hipStream_t stream) {
    const float* x = (const float*)d_in[0];   // [8192, 4096]
    const float* W = (const float*)d_in[1];   // [4096, 4096]
    const float* b = (const float*)d_in[2];   // [4096]
    float* out = (float*)d_out;               // [8192, 4096]

    constexpr size_t T = 8192, DIN = 4096, DOUT = 4096;
    const size_t nx = T * DIN, nw = DOUT * DIN;

    if (ws_size >= (nx + nw) * sizeof(unsigned short)) {
        unsigned short* xbf = (unsigned short*)d_ws;
        unsigned short* wbf = xbf + nx;
        cast_both<<<24576, 256, 0, stream>>>((const f32x4*)x, (u32x4*)xbf,
                                             (const f32x4*)W, (u32x4*)wbf);
        // 256x256 tiles: 32 x 16 = 512 blocks, 512 threads
        gemm256<<<512, 512, 0, stream>>>(xbf, wbf, b, out);
    } else {
        dim3 grid(DOUT / 32, T / 32);
        gemm_f32_fallback<<<grid, 256, 0, stream>>>(x, W, b, out);
    }
}